// Round 1
// baseline (291.668 us; speedup 1.0000x reference)
//
#include <hip/hip_runtime.h>
#include <hip/hip_bf16.h>
#include <stdint.h>
#include <stddef.h>

// ---------------------------------------------------------------------------
// Quantized LSTM cell (B=4096, I=H=1024) with JAX threefry noise reproduction.
//
// gates = qS8(input) @ (Wih^T + n0) + b_ih + nb0 + qS8(hx) @ (Whh^T + n1) + b_hh + nb1
// Folded into ONE bf16 MFMA GEMM:  M=N=K=4096
//   A  [4096][2048]  = [qS8(input) | qS8(hx)]           (exact in bf16)
//   B^T[4096][4096]  = rows k<2048: bf16_hi(Weff), k>=2048: bf16_lo(Weff)
//   A column for k>=2048 is read as k&2047 (same activations, lo-residual pass)
// ---------------------------------------------------------------------------

#define PART 1  // 1 = jax threefry_partitionable (default since jax 0.4.30)

typedef __attribute__((ext_vector_type(8))) short bf16x8;
typedef __attribute__((ext_vector_type(4))) float f32x4;

#define BATCH 4096
#define NG    4096
#define KREAL 2048

// ---- workspace layout (bytes) ----
#define WS_A_OFF    ((size_t)0)                 // ushort[4096*2048]   16 MiB
#define WS_B_OFF    ((size_t)16 << 20)          // ushort[4096*4096]   32 MiB
#define WS_G_OFF    ((size_t)48 << 20)          // float [4096*4096]   64 MiB
#define WS_BIAS_OFF ((size_t)112 << 20)         // float [4096]
#define WS_MAX_OFF  (WS_BIAS_OFF + 16384)       // uint32[4]

// ---------------- threefry2x32 (exact JAX algorithm) ----------------
__host__ __device__ inline void tf2x32(uint32_t k0, uint32_t k1,
                                       uint32_t x0, uint32_t x1,
                                       uint32_t &o0, uint32_t &o1)
{
  const uint32_t k2 = k0 ^ k1 ^ 0x1BD11BDAu;
#define TFR(r) { x0 += x1; x1 = (x1 << (r)) | (x1 >> (32 - (r))); x1 ^= x0; }
  x0 += k0; x1 += k1;
  TFR(13) TFR(15) TFR(26) TFR(6)
  x0 += k1; x1 += k2 + 1u;
  TFR(17) TFR(29) TFR(16) TFR(24)
  x0 += k2; x1 += k0 + 2u;
  TFR(13) TFR(15) TFR(26) TFR(6)
  x0 += k0; x1 += k1 + 3u;
  TFR(17) TFR(29) TFR(16) TFR(24)
  x0 += k1; x1 += k2 + 4u;
  TFR(13) TFR(15) TFR(26) TFR(6)
  x0 += k2; x1 += k0 + 5u;
#undef TFR
  o0 = x0; o1 = x1;
}

// bits for flat element i of an array of `size` 32-bit draws
__device__ inline uint32_t jax_bits32(uint32_t k0, uint32_t k1, uint32_t i, uint32_t size)
{
#if PART
  uint32_t a, b;
  tf2x32(k0, k1, 0u, i, a, b);     // counts = (hi32(i), lo32(i)) = (0, i)
  return a ^ b;
#else
  uint32_t half = size >> 1, a, b;
  if (i < half) { tf2x32(k0, k1, i, i + half, a, b); return a; }
  tf2x32(k0, k1, i - half, i, a, b); return b;
#endif
}

// uniform(-1+2^-24, 1) -> sqrt(2)*erfinv(u), XLA f32 ErfInv (Giles) polynomial
__device__ inline float bits_to_normal(uint32_t bits)
{
  float f = __uint_as_float((bits >> 9) | 0x3F800000u) - 1.0f;  // [0,1)
  const float lo = -0x1.fffffep-1f;          // nextafter(-1f, 0f)
  float u = fmaxf(lo, f * 2.0f + lo);        // (hi-lo) rounds to exactly 2.0f
  float w = -log1pf(-u * u);
  float p;
  if (w < 5.0f) {
    w -= 2.5f;
    p = 2.81022636e-08f;
    p = fmaf(p, w, 3.43273939e-07f);
    p = fmaf(p, w, -3.5233877e-06f);
    p = fmaf(p, w, -4.39150654e-06f);
    p = fmaf(p, w, 0.00021858087f);
    p = fmaf(p, w, -0.00125372503f);
    p = fmaf(p, w, -0.00417768164f);
    p = fmaf(p, w, 0.246640727f);
    p = fmaf(p, w, 1.50140941f);
  } else {
    w = sqrtf(w) - 3.0f;
    p = -0.000200214257f;
    p = fmaf(p, w, 0.000100950558f);
    p = fmaf(p, w, 0.00134934322f);
    p = fmaf(p, w, -0.00367342844f);
    p = fmaf(p, w, 0.00573950773f);
    p = fmaf(p, w, -0.0076224613f);
    p = fmaf(p, w, 0.00943887047f);
    p = fmaf(p, w, 1.00167406f);
    p = fmaf(p, w, 2.83297682f);
  }
  return 0x1.6a09e6p+0f * (p * u);  // f32(sqrt(2)) * erfinv(u)
}

// ---------------- quantization helpers (match quant_pass exactly) -----------
__device__ inline float quantS8(float x)   // wb=8, sign=True: clip +/-(1-1/128), grid 1/128
{
  x = fminf(fmaxf(x, -0.9921875f), 0.9921875f);
  return rintf(x * 128.0f) * 0.0078125f;    // rintf = round half to even = jnp.round
}
__device__ inline float quantU8(float x)   // wb=8, sign=False: clip [0,1], grid 1/256
{
  x = fminf(fmaxf(x, 0.0f), 1.0f);
  return rintf(x * 256.0f) * 0.00390625f;
}
__device__ inline float sigmoid_xla(float x) { return 0.5f + 0.5f * tanhf(0.5f * x); }

// bf16 bit helpers (RNE, matches hardware cvt)
__device__ inline unsigned short f2bf(float x)
{
  uint32_t b = __float_as_uint(x);
  return (unsigned short)((b + 0x7FFFu + ((b >> 16) & 1u)) >> 16);
}
__device__ inline float bf2f(unsigned short u) { return __uint_as_float(((uint32_t)u) << 16); }

// ordered-uint encoding for float atomicMax
__device__ inline float dec_max(uint32_t u)
{
  uint32_t bits = (u & 0x80000000u) ? (u ^ 0x80000000u) : ~u;
  return __uint_as_float(bits);
}

// ---------------- kernels ----------------
__global__ void init_max(uint32_t* mx)
{
  if (threadIdx.x < 4) mx[threadIdx.x] = 0u;  // encoded lower bound
}

__global__ void kmax(const float4* __restrict__ a, int n4, uint32_t* __restrict__ out)
{
  float m = -3.4e38f;
  for (int i = blockIdx.x * blockDim.x + threadIdx.x; i < n4; i += gridDim.x * blockDim.x) {
    float4 v = a[i];
    m = fmaxf(fmaxf(m, fmaxf(v.x, v.y)), fmaxf(v.z, v.w));
  }
  for (int off = 32; off; off >>= 1) m = fmaxf(m, __shfl_down(m, off, 64));
  __shared__ float sm[4];
  if ((threadIdx.x & 63) == 0) sm[threadIdx.x >> 6] = m;
  __syncthreads();
  if (threadIdx.x == 0) {
    float bm = sm[0];
    for (int w = 1; w < (int)(blockDim.x >> 6); ++w) bm = fmaxf(bm, sm[w]);
    uint32_t bits = __float_as_uint(bm);
    uint32_t enc = (bits & 0x80000000u) ? ~bits : (bits | 0x80000000u);
    atomicMax(out, enc);
  }
}

// A[b][k] = bf16(qS8( k<1024 ? input[b][k] : hx[b][k-1024] ))  -- exact in bf16
__global__ void build_A(const float4* __restrict__ in, const float4* __restrict__ hx,
                        unsigned short* __restrict__ A)
{
  int t = blockIdx.x * 256 + threadIdx.x;           // 2,097,152 threads (4 elems each)
  int b = t >> 9;                                   // 512 float4 per 2048-row
  int kq = t & 511;
  float4 v = (kq < 256) ? in[b * 256 + kq] : hx[b * 256 + (kq - 256)];
  unsigned short o[4];
  o[0] = f2bf(quantS8(v.x)); o[1] = f2bf(quantS8(v.y));
  o[2] = f2bf(quantS8(v.z)); o[3] = f2bf(quantS8(v.w));
  *reinterpret_cast<uint64_t*>(A + (size_t)t * 4) = *reinterpret_cast<uint64_t*>(o);
}

// B^T[n][kc] with kc<2048: hi(Weff), kc>=2048: lo residual. Weff = W^T + noise.
__global__ void build_B(const float* __restrict__ wih, const float* __restrict__ whh,
                        unsigned short* __restrict__ B, const uint32_t* __restrict__ mxenc,
                        uint32_t kih0, uint32_t kih1, uint32_t khh0, uint32_t khh1)
{
  uint32_t t = blockIdx.x * 256u + threadIdx.x;     // 8,388,608 threads
  uint32_t arr = t >> 22;                           // 0: ih, 1: hh
  uint32_t r = t & 4194303u;
  uint32_t k = r & 1023u;                           // k within [0,1024)
  uint32_t n = r >> 10;                             // output column [0,4096)
  const float* w = arr ? whh : wih;
  float mx = dec_max(mxenc[arr]);
  uint32_t key0 = arr ? khh0 : kih0, key1 = arr ? khh1 : kih1;
  uint32_t i = k * 4096u + n;                       // noise flat index, shape (1024,4096)
  float nrm = bits_to_normal(jax_bits32(key0, key1, i, 4194304u));
  float weff = w[(size_t)n * 1024u + k] + (nrm * mx) * 0.05f;
  unsigned short hi = f2bf(weff);
  unsigned short lob = f2bf(weff - bf2f(hi));
  size_t base = (size_t)n * 4096u + (arr ? 1024u : 0u) + k;
  B[base] = hi;
  B[base + 2048u] = lob;
}

__global__ void build_bias(const float* __restrict__ bih, const float* __restrict__ bhh,
                           float* __restrict__ biasE, const uint32_t* __restrict__ mxenc,
                           uint32_t kbi0, uint32_t kbi1, uint32_t kbh0, uint32_t kbh1)
{
  uint32_t j = blockIdx.x * 256u + threadIdx.x;
  if (j >= 4096u) return;
  float mi = dec_max(mxenc[2]), mh = dec_max(mxenc[3]);
  float ni = (bits_to_normal(jax_bits32(kbi0, kbi1, j, 4096u)) * mi) * 0.05f;
  float nh = (bits_to_normal(jax_bits32(kbh0, kbh1, j, 4096u)) * mh) * 0.05f;
  biasE[j] = ((bih[j] + ni) + bhh[j]) + nh;
}

// ---------------- MFMA GEMM: gates[M=4096][N=4096] = A' @ B^T + bias --------
__device__ __forceinline__ void gload_lds16(const void* g, void* l)
{
  __builtin_amdgcn_global_load_lds((__attribute__((address_space(1))) void*)g,
                                   (__attribute__((address_space(3))) void*)l, 16, 0, 0);
}

__global__ __launch_bounds__(256, 2) void gemm_gates(
    const unsigned short* __restrict__ A,   // [4096][2048] bf16 bits
    const unsigned short* __restrict__ B,   // [4096][4096] bf16 bits, N-major
    const float* __restrict__ bias,         // [4096]
    float* __restrict__ gates)              // [4096][4096]
{
  __shared__ unsigned short As[128 * 64];   // 16 KiB
  __shared__ unsigned short Bs[128 * 64];   // 16 KiB
  const int tid  = threadIdx.x;
  const int lane = tid & 63;
  const int wave = tid >> 6;
  const int wr = (wave >> 1) * 64;          // wave's M offset in tile
  const int wc = (wave & 1) * 64;           // wave's N offset in tile
  const int brow = blockIdx.y * 128;
  const int bcol = blockIdx.x * 128;

  const int srow = tid >> 3;                // staging row within 32-row chunk
  const int scol = (tid & 7) * 8;           // staging col (elements)
  const int lrow = lane & 15;
  const int lk   = (lane >> 4) * 8;

  f32x4 acc[4][4] = {};

  for (int kt = 0; kt < 4096; kt += 64) {
    __syncthreads();
    const int ka = kt & 2047;               // A columns repeat for the lo half
#pragma unroll
    for (int c = 0; c < 4; ++c) {
      const int row = c * 32 + srow;
      gload_lds16(A + (size_t)(brow + row) * 2048 + ka + scol, (void*)(As + c * 2048 + tid * 8));
      gload_lds16(B + (size_t)(bcol + row) * 4096 + kt + scol, (void*)(Bs + c * 2048 + tid * 8));
    }
    __syncthreads();                        // drains vmcnt (global_load_lds) + lgkm
#pragma unroll
    for (int ks = 0; ks < 64; ks += 32) {
      bf16x8 af[4], bfr[4];
#pragma unroll
      for (int m = 0; m < 4; ++m)
        af[m] = *(const bf16x8*)(As + (wr + m * 16 + lrow) * 64 + ks + lk);
#pragma unroll
      for (int n = 0; n < 4; ++n)
        bfr[n] = *(const bf16x8*)(Bs + (wc + n * 16 + lrow) * 64 + ks + lk);
#pragma unroll
      for (int m = 0; m < 4; ++m)
#pragma unroll
        for (int n = 0; n < 4; ++n)
          acc[m][n] = __builtin_amdgcn_mfma_f32_16x16x32_bf16(af[m], bfr[n], acc[m][n], 0, 0, 0);
    }
  }

  // C/D layout (m89-verified): col = lane&15, row = (lane>>4)*4 + reg
  const int orow0 = brow + wr + ((lane >> 4) << 2);
  const int ocol0 = bcol + wc + (lane & 15);
#pragma unroll
  for (int m = 0; m < 4; ++m) {
#pragma unroll
    for (int n = 0; n < 4; ++n) {
      const int col = ocol0 + n * 16;
      const float bv = bias[col];
#pragma unroll
      for (int r = 0; r < 4; ++r) {
        const int row = orow0 + m * 16 + r;
        gates[(size_t)row * 4096 + col] = acc[m][n][r] + bv;
      }
    }
  }
}

// ---------------- elementwise LSTM epilogue ----------------
__global__ void lstm_ew(const float* __restrict__ gates, const float* __restrict__ cx,
                        float* __restrict__ hy, float* __restrict__ cy)
{
  int idx = blockIdx.x * 256 + threadIdx.x;   // 4,194,304 threads
  int b = idx >> 10, h = idx & 1023;
  const float* g = gates + (size_t)b * 4096;
  float ing = quantU8(sigmoid_xla(g[h]));
  float fg  = quantU8(sigmoid_xla(g[h + 1024]));
  float cg  = quantS8(tanhf(g[h + 2048]));
  float og  = quantU8(sigmoid_xla(g[h + 3072]));
  float c0  = cx[idx];
  float cyv = quantS8((quantS8(fg * c0) + quantS8(ing * cg)) * 0.5f);  // /CY_DIV exact
  float hyv = quantS8(og * quantS8(tanhf(cyv * 2.0f)));                // CY_SCALE
  hy[idx] = hyv;
  cy[idx] = cyv;
}

// ---------------- host ----------------
extern "C" void kernel_launch(void* const* d_in, const int* in_sizes, int n_in,
                              void* d_out, int out_size, void* d_ws, size_t ws_size,
                              hipStream_t stream)
{
  const float* input = (const float*)d_in[0];
  const float* hx    = (const float*)d_in[1];
  const float* cx    = (const float*)d_in[2];
  const float* wih   = (const float*)d_in[3];
  const float* whh   = (const float*)d_in[4];
  const float* bih   = (const float*)d_in[5];
  const float* bhh   = (const float*)d_in[6];
  (void)in_sizes; (void)n_in; (void)ws_size;

  uint8_t* ws = (uint8_t*)d_ws;
  unsigned short* A   = (unsigned short*)(ws + WS_A_OFF);
  unsigned short* B   = (unsigned short*)(ws + WS_B_OFF);
  float* gates        = (float*)(ws + WS_G_OFF);
  float* biasE        = (float*)(ws + WS_BIAS_OFF);
  uint32_t* mx        = (uint32_t*)(ws + WS_MAX_OFF);

  // key(42) = (0,42); nk = split(key, 4) computed on host (pure integer code)
  uint32_t nk[4][2];
#if PART
  for (int i = 0; i < 4; ++i) tf2x32(0u, 42u, 0u, (uint32_t)i, nk[i][0], nk[i][1]);
#else
  {
    uint32_t w0[4], w1[4];
    for (int i = 0; i < 4; ++i) tf2x32(0u, 42u, (uint32_t)i, (uint32_t)(i + 4), w0[i], w1[i]);
    uint32_t out8[8] = {w0[0], w0[1], w0[2], w0[3], w1[0], w1[1], w1[2], w1[3]};
    for (int i = 0; i < 4; ++i) { nk[i][0] = out8[2 * i]; nk[i][1] = out8[2 * i + 1]; }
  }
#endif

  init_max<<<1, 64, 0, stream>>>(mx);
  kmax<<<1024, 256, 0, stream>>>((const float4*)wih, 1048576, mx + 0);
  kmax<<<1024, 256, 0, stream>>>((const float4*)whh, 1048576, mx + 1);
  kmax<<<4, 256, 0, stream>>>((const float4*)bih, 1024, mx + 2);
  kmax<<<4, 256, 0, stream>>>((const float4*)bhh, 1024, mx + 3);

  build_A<<<8192, 256, 0, stream>>>((const float4*)input, (const float4*)hx, A);
  build_B<<<32768, 256, 0, stream>>>(wih, whh, B, mx, nk[0][0], nk[0][1], nk[1][0], nk[1][1]);
  build_bias<<<16, 256, 0, stream>>>(bih, bhh, biasE, mx, nk[2][0], nk[2][1], nk[3][0], nk[3][1]);

  dim3 grid(32, 32);
  gemm_gates<<<grid, 256, 0, stream>>>(A, B, biasE, gates);

  float* hy = (float*)d_out;
  float* cyp = hy + (size_t)BATCH * 1024;
  lstm_ew<<<16384, 256, 0, stream>>>(gates, cx, hy, cyp);
}

// Round 2
// 233.565 us; speedup vs baseline: 1.2488x; 1.2488x over previous
//
#include <hip/hip_runtime.h>
#include <hip/hip_bf16.h>
#include <stdint.h>
#include <stddef.h>

// ---------------------------------------------------------------------------
// Quantized LSTM cell (B=4096, I=H=1024) with JAX threefry noise reproduction.
//
// gates = qS8(input) @ (Wih^T + n0) + b_ih + nb0 + qS8(hx) @ (Whh^T + n1) + b_hh + nb1
// Folded into ONE bf16 MFMA GEMM:  M=N=K=4096
//   A  [4096][2048]  = [qS8(input) | qS8(hx)]           (exact in bf16)
//   B^T[4096][4096]  = rows k<2048: bf16_hi(Weff), k>=2048: bf16_lo(Weff)
//   A column for k>=2048 is read as k&2047 (same activations, lo-residual pass)
//
// GEMM: 256x256 tile, BK=32, 8 waves, 4-deep LDS pipeline (128KB dynamic),
// counted vmcnt(4), XOR-swizzled LDS (T2), setprio around MFMA (T5).
// ---------------------------------------------------------------------------

#define PART 1  // jax threefry_partitionable (verified correct in round 1)

typedef __attribute__((ext_vector_type(8))) short bf16x8;
typedef __attribute__((ext_vector_type(4))) float f32x4;

#define BATCH 4096

// ---- workspace layout (bytes) ----
#define WS_A_OFF    ((size_t)0)                 // ushort[4096*2048]   16 MiB
#define WS_B_OFF    ((size_t)16 << 20)          // ushort[4096*4096]   32 MiB
#define WS_G_OFF    ((size_t)48 << 20)          // float [4096*4096]   64 MiB
#define WS_BIAS_OFF ((size_t)112 << 20)         // float [4096]
#define WS_MAX_OFF  (WS_BIAS_OFF + 16384)       // uint32[4]

// ---------------- threefry2x32 (exact JAX algorithm) ----------------
__host__ __device__ inline void tf2x32(uint32_t k0, uint32_t k1,
                                       uint32_t x0, uint32_t x1,
                                       uint32_t &o0, uint32_t &o1)
{
  const uint32_t k2 = k0 ^ k1 ^ 0x1BD11BDAu;
#define TFR(r) { x0 += x1; x1 = (x1 << (r)) | (x1 >> (32 - (r))); x1 ^= x0; }
  x0 += k0; x1 += k1;
  TFR(13) TFR(15) TFR(26) TFR(6)
  x0 += k1; x1 += k2 + 1u;
  TFR(17) TFR(29) TFR(16) TFR(24)
  x0 += k2; x1 += k0 + 2u;
  TFR(13) TFR(15) TFR(26) TFR(6)
  x0 += k0; x1 += k1 + 3u;
  TFR(17) TFR(29) TFR(16) TFR(24)
  x0 += k1; x1 += k2 + 4u;
  TFR(13) TFR(15) TFR(26) TFR(6)
  x0 += k2; x1 += k0 + 5u;
#undef TFR
  o0 = x0; o1 = x1;
}

__device__ inline uint32_t jax_bits32(uint32_t k0, uint32_t k1, uint32_t i, uint32_t size)
{
#if PART
  uint32_t a, b;
  tf2x32(k0, k1, 0u, i, a, b);
  return a ^ b;
#else
  uint32_t half = size >> 1, a, b;
  if (i < half) { tf2x32(k0, k1, i, i + half, a, b); return a; }
  tf2x32(k0, k1, i - half, i, a, b); return b;
#endif
}

// uniform(-1+2^-24, 1) -> sqrt(2)*erfinv(u), XLA f32 ErfInv (Giles) polynomial
__device__ inline float bits_to_normal(uint32_t bits)
{
  float f = __uint_as_float((bits >> 9) | 0x3F800000u) - 1.0f;  // [0,1)
  const float lo = -0x1.fffffep-1f;
  float u = fmaxf(lo, f * 2.0f + lo);
  float w = -log1pf(-u * u);
  float p;
  if (w < 5.0f) {
    w -= 2.5f;
    p = 2.81022636e-08f;
    p = fmaf(p, w, 3.43273939e-07f);
    p = fmaf(p, w, -3.5233877e-06f);
    p = fmaf(p, w, -4.39150654e-06f);
    p = fmaf(p, w, 0.00021858087f);
    p = fmaf(p, w, -0.00125372503f);
    p = fmaf(p, w, -0.00417768164f);
    p = fmaf(p, w, 0.246640727f);
    p = fmaf(p, w, 1.50140941f);
  } else {
    w = sqrtf(w) - 3.0f;
    p = -0.000200214257f;
    p = fmaf(p, w, 0.000100950558f);
    p = fmaf(p, w, 0.00134934322f);
    p = fmaf(p, w, -0.00367342844f);
    p = fmaf(p, w, 0.00573950773f);
    p = fmaf(p, w, -0.0076224613f);
    p = fmaf(p, w, 0.00943887047f);
    p = fmaf(p, w, 1.00167406f);
    p = fmaf(p, w, 2.83297682f);
  }
  return 0x1.6a09e6p+0f * (p * u);
}

// ---------------- quantization helpers ----------------
__device__ inline float quantS8(float x)
{
  x = fminf(fmaxf(x, -0.9921875f), 0.9921875f);
  return rintf(x * 128.0f) * 0.0078125f;
}
__device__ inline float quantU8(float x)
{
  x = fminf(fmaxf(x, 0.0f), 1.0f);
  return rintf(x * 256.0f) * 0.00390625f;
}
__device__ inline float sigmoid_xla(float x) { return 0.5f + 0.5f * tanhf(0.5f * x); }

__device__ inline unsigned short f2bf(float x)
{
  uint32_t b = __float_as_uint(x);
  return (unsigned short)((b + 0x7FFFu + ((b >> 16) & 1u)) >> 16);
}
__device__ inline float bf2f(unsigned short u) { return __uint_as_float(((uint32_t)u) << 16); }

__device__ inline float dec_max(uint32_t u)
{
  uint32_t bits = (u & 0x80000000u) ? (u ^ 0x80000000u) : ~u;
  return __uint_as_float(bits);
}

// ---------------- small kernels (unchanged from round 1) ----------------
__global__ void init_max(uint32_t* mx)
{
  if (threadIdx.x < 4) mx[threadIdx.x] = 0u;
}

__global__ void kmax(const float4* __restrict__ a, int n4, uint32_t* __restrict__ out)
{
  float m = -3.4e38f;
  for (int i = blockIdx.x * blockDim.x + threadIdx.x; i < n4; i += gridDim.x * blockDim.x) {
    float4 v = a[i];
    m = fmaxf(fmaxf(m, fmaxf(v.x, v.y)), fmaxf(v.z, v.w));
  }
  for (int off = 32; off; off >>= 1) m = fmaxf(m, __shfl_down(m, off, 64));
  __shared__ float sm[4];
  if ((threadIdx.x & 63) == 0) sm[threadIdx.x >> 6] = m;
  __syncthreads();
  if (threadIdx.x == 0) {
    float bm = sm[0];
    for (int w = 1; w < (int)(blockDim.x >> 6); ++w) bm = fmaxf(bm, sm[w]);
    uint32_t bits = __float_as_uint(bm);
    uint32_t enc = (bits & 0x80000000u) ? ~bits : (bits | 0x80000000u);
    atomicMax(out, enc);
  }
}

__global__ void build_A(const float4* __restrict__ in, const float4* __restrict__ hx,
                        unsigned short* __restrict__ A)
{
  int t = blockIdx.x * 256 + threadIdx.x;
  int b = t >> 9;
  int kq = t & 511;
  float4 v = (kq < 256) ? in[b * 256 + kq] : hx[b * 256 + (kq - 256)];
  unsigned short o[4];
  o[0] = f2bf(quantS8(v.x)); o[1] = f2bf(quantS8(v.y));
  o[2] = f2bf(quantS8(v.z)); o[3] = f2bf(quantS8(v.w));
  *reinterpret_cast<uint64_t*>(A + (size_t)t * 4) = *reinterpret_cast<uint64_t*>(o);
}

__global__ void build_B(const float* __restrict__ wih, const float* __restrict__ whh,
                        unsigned short* __restrict__ B, const uint32_t* __restrict__ mxenc,
                        uint32_t kih0, uint32_t kih1, uint32_t khh0, uint32_t khh1)
{
  uint32_t t = blockIdx.x * 256u + threadIdx.x;
  uint32_t arr = t >> 22;
  uint32_t r = t & 4194303u;
  uint32_t k = r & 1023u;
  uint32_t n = r >> 10;
  const float* w = arr ? whh : wih;
  float mx = dec_max(mxenc[arr]);
  uint32_t key0 = arr ? khh0 : kih0, key1 = arr ? khh1 : kih1;
  uint32_t i = k * 4096u + n;
  float nrm = bits_to_normal(jax_bits32(key0, key1, i, 4194304u));
  float weff = w[(size_t)n * 1024u + k] + (nrm * mx) * 0.05f;
  unsigned short hi = f2bf(weff);
  unsigned short lob = f2bf(weff - bf2f(hi));
  size_t base = (size_t)n * 4096u + (arr ? 1024u : 0u) + k;
  B[base] = hi;
  B[base + 2048u] = lob;
}

__global__ void build_bias(const float* __restrict__ bih, const float* __restrict__ bhh,
                           float* __restrict__ biasE, const uint32_t* __restrict__ mxenc,
                           uint32_t kbi0, uint32_t kbi1, uint32_t kbh0, uint32_t kbh1)
{
  uint32_t j = blockIdx.x * 256u + threadIdx.x;
  if (j >= 4096u) return;
  float mi = dec_max(mxenc[2]), mh = dec_max(mxenc[3]);
  float ni = (bits_to_normal(jax_bits32(kbi0, kbi1, j, 4096u)) * mi) * 0.05f;
  float nh = (bits_to_normal(jax_bits32(kbh0, kbh1, j, 4096u)) * mh) * 0.05f;
  biasE[j] = ((bih[j] + ni) + bhh[j]) + nh;
}

// ---------------- deep-pipelined MFMA GEMM -----------------------------
// BM=BN=256, BK=32, 512 threads = 8 waves (2M x 4N). 4 LDS buffers of
// (A 16KB + B 16KB). Staging runs 2 K-tiles ahead; vmcnt(4) counted waits.
//
// LDS unit layout (16KB, logical [256 rows][32 k] bf16):
//   phys_byte(r,k) = (r>>1)*128 + (((r&1)*4 + (k>>3)) ^ ((r>>1)&7))*16 + (k&7)*2
// Staged via linear global_load_lds dest + inverse-swizzled global source.
// ds_read_b128 fragment reads then have a per-lane-constant chunk -> 2-way
// bank aliasing only (free).

__device__ __forceinline__ void gload_lds16(const void* g, void* l)
{
  __builtin_amdgcn_global_load_lds((__attribute__((address_space(1))) void*)g,
                                   (__attribute__((address_space(3))) void*)l, 16, 0, 0);
}

#define VM4  asm volatile("s_waitcnt vmcnt(4)" ::: "memory")
#define VM0  asm volatile("s_waitcnt vmcnt(0)" ::: "memory")
#define NOVM

#define TILE_ONE(t_, DO_STAGE_, VM_ASM_)                                          \
  {                                                                               \
    const int buf_ = (t_) & 3;                                                    \
    const unsigned char* pa_ = lds + buf_ * 32768 + aoff;                         \
    const unsigned char* pb_ = lds + buf_ * 32768 + boff;                         \
    bf16x8 bfr_[4], af_[4];                                                       \
    _Pragma("unroll") for (int n_ = 0; n_ < 4; ++n_)                              \
      bfr_[n_] = *(const bf16x8*)(pb_ + n_ * 1024);                               \
    _Pragma("unroll") for (int m_ = 0; m_ < 4; ++m_)                              \
      af_[m_] = *(const bf16x8*)(pa_ + m_ * 1024);                                \
    if (DO_STAGE_) {                                                              \
      const int ts_ = (t_) + 2;                                                   \
      unsigned char* la_ = lds + (ts_ & 3) * 32768;                               \
      const int ka_ = (ts_ * 32) & 2047;                                          \
      gload_lds16(Ar0 + ka_, la_ + tid * 16);                                     \
      gload_lds16(Ar1 + ka_, la_ + 8192 + tid * 16);                              \
    }                                                                             \
    __builtin_amdgcn_s_barrier();                                                 \
    __builtin_amdgcn_sched_barrier(0);                                            \
    __builtin_amdgcn_s_setprio(1);                                                \
    _Pragma("unroll") for (int m_ = 0; m_ < 4; ++m_)                              \
      _Pragma("unroll") for (int n_ = 0; n_ < 4; ++n_)                            \
        acc[m_][n_] = __builtin_amdgcn_mfma_f32_16x16x32_bf16(af_[m_], bfr_[n_],  \
                                                              acc[m_][n_], 0, 0, 0); \
    __builtin_amdgcn_s_setprio(0);                                                \
    __builtin_amdgcn_s_barrier();                                                 \
    __builtin_amdgcn_sched_barrier(0);                                            \
    _Pragma("unroll") for (int m_ = 0; m_ < 4; ++m_)                              \
      af_[m_] = *(const bf16x8*)(pa_ + (4 + m_) * 1024);                          \
    if (DO_STAGE_) {                                                              \
      const int ts_ = (t_) + 2;                                                   \
      unsigned char* lb_ = lds + (ts_ & 3) * 32768 + 16384;                       \
      const size_t kb_ = (size_t)ts_ * 32;                                        \
      gload_lds16(Br0 + kb_, lb_ + tid * 16);                                     \
      gload_lds16(Br1 + kb_, lb_ + 8192 + tid * 16);                              \
    }                                                                             \
    __builtin_amdgcn_s_barrier();                                                 \
    __builtin_amdgcn_sched_barrier(0);                                            \
    __builtin_amdgcn_s_setprio(1);                                                \
    _Pragma("unroll") for (int m_ = 0; m_ < 4; ++m_)                              \
      _Pragma("unroll") for (int n_ = 0; n_ < 4; ++n_)                            \
        acc[4 + m_][n_] = __builtin_amdgcn_mfma_f32_16x16x32_bf16(af_[m_], bfr_[n_], \
                                                              acc[4 + m_][n_], 0, 0, 0); \
    __builtin_amdgcn_s_setprio(0);                                                \
    VM_ASM_;                                                                      \
    __builtin_amdgcn_s_barrier();                                                 \
    __builtin_amdgcn_sched_barrier(0);                                            \
  }

__global__ __launch_bounds__(512, 2) void gemm_gates(
    const unsigned short* __restrict__ A,   // [4096][2048] bf16 bits
    const unsigned short* __restrict__ B,   // [4096][4096] bf16 bits, N-major
    const float* __restrict__ bias,         // [4096]
    float* __restrict__ gates)              // [4096][4096]
{
  extern __shared__ unsigned char lds[];    // 4 * 32KB = 128KB
  const int tid  = threadIdx.x;
  const int lane = tid & 63;
  const int wave = tid >> 6;
  const int wr = wave >> 2;                 // 0..1  (M)
  const int wc = wave & 3;                  // 0..3  (N)

  // XCD-chunked swizzle: 256 blocks, XCD x owns wg in [32x, 32x+32);
  // bcol band per XCD (B panel 4MB -> fits per-XCD L2).
  const int bid = blockIdx.x;
  const int wg  = (bid & 7) * 32 + (bid >> 3);
  const int brow = (wg & 15) * 256;
  const int bcol = (wg >> 4) * 256;

  // staging source precompute: chunk c -> p=c>>3, lc=(c&7)^(p&7),
  // r = 2p + (lc>>2), k = (lc&3)*8
  int sr0, sk0, sr1, sk1;
  {
    int c = tid, p = c >> 3, lc = (c & 7) ^ (p & 7);
    sr0 = p * 2 + (lc >> 2); sk0 = (lc & 3) * 8;
    c = tid + 512; p = c >> 3; lc = (c & 7) ^ (p & 7);
    sr1 = p * 2 + (lc >> 2); sk1 = (lc & 3) * 8;
  }
  const unsigned short* Ar0 = A + (size_t)(brow + sr0) * 2048 + sk0;
  const unsigned short* Ar1 = A + (size_t)(brow + sr1) * 2048 + sk1;
  const unsigned short* Br0 = B + (size_t)(bcol + sr0) * 4096 + sk0;
  const unsigned short* Br1 = B + (size_t)(bcol + sr1) * 4096 + sk1;

  // ds_read per-lane constants: frag (r = base + m*16 + (lane&15), k=(lane>>4)*8)
  const int lrh = (lane & 15) >> 1;
  const int chk = ((((lane & 1) << 2) | (lane >> 4)) ^ lrh);
  const int aoff = wr * 8192 + lrh * 128 + chk * 16;            // + m*1024
  const int boff = 16384 + wc * 4096 + lrh * 128 + chk * 16;    // + n*1024

  f32x4 acc[8][4] = {};

  // prologue: stage tiles 0,1 -> bufs 0,1 (per-thread order A,B,A,B)
#pragma unroll
  for (int tt = 0; tt < 2; ++tt) {
    unsigned char* la = lds + tt * 32768;
    const int ka = tt * 32;
    gload_lds16(Ar0 + ka, la + tid * 16);
    gload_lds16(Ar1 + ka, la + 8192 + tid * 16);
    gload_lds16(Br0 + (size_t)(tt * 32), la + 16384 + tid * 16);
    gload_lds16(Br1 + (size_t)(tt * 32), la + 16384 + 8192 + tid * 16);
  }
  VM4;                                       // retire A(0),B(0); A(1),B(1) in flight
  __builtin_amdgcn_s_barrier();
  __builtin_amdgcn_sched_barrier(0);

#pragma unroll 1
  for (int t = 0; t < 126; ++t) {
    TILE_ONE(t, 1, VM4);
  }
  TILE_ONE(126, 0, VM0);
  TILE_ONE(127, 0, NOVM);

  // C/D layout: col = lane&15, row = (lane>>4)*4 + reg
  const int orow0 = brow + wr * 128 + ((lane >> 4) << 2);
  const int ocol0 = bcol + wc * 64 + (lane & 15);
#pragma unroll
  for (int n = 0; n < 4; ++n) {
    const int col = ocol0 + n * 16;
    const float bv = bias[col];
#pragma unroll
    for (int m = 0; m < 8; ++m) {
#pragma unroll
      for (int r = 0; r < 4; ++r)
        gates[(size_t)(orow0 + m * 16 + r) * 4096 + col] = acc[m][n][r] + bv;
    }
  }
}

// ---------------- elementwise LSTM epilogue ----------------
__global__ void lstm_ew(const float* __restrict__ gates, const float* __restrict__ cx,
                        float* __restrict__ hy, float* __restrict__ cy)
{
  int idx = blockIdx.x * 256 + threadIdx.x;
  int b = idx >> 10, h = idx & 1023;
  const float* g = gates + (size_t)b * 4096;
  float ing = quantU8(sigmoid_xla(g[h]));
  float fg  = quantU8(sigmoid_xla(g[h + 1024]));
  float cg  = quantS8(tanhf(g[h + 2048]));
  float og  = quantU8(sigmoid_xla(g[h + 3072]));
  float c0  = cx[idx];
  float cyv = quantS8((quantS8(fg * c0) + quantS8(ing * cg)) * 0.5f);
  float hyv = quantS8(og * quantS8(tanhf(cyv * 2.0f)));
  hy[idx] = hyv;
  cy[idx] = cyv;
}

// ---------------- host ----------------
extern "C" void kernel_launch(void* const* d_in, const int* in_sizes, int n_in,
                              void* d_out, int out_size, void* d_ws, size_t ws_size,
                              hipStream_t stream)
{
  const float* input = (const float*)d_in[0];
  const float* hx    = (const float*)d_in[1];
  const float* cx    = (const float*)d_in[2];
  const float* wih   = (const float*)d_in[3];
  const float* whh   = (const float*)d_in[4];
  const float* bih   = (const float*)d_in[5];
  const float* bhh   = (const float*)d_in[6];
  (void)in_sizes; (void)n_in; (void)ws_size;

  uint8_t* ws = (uint8_t*)d_ws;
  unsigned short* A   = (unsigned short*)(ws + WS_A_OFF);
  unsigned short* B   = (unsigned short*)(ws + WS_B_OFF);
  float* gates        = (float*)(ws + WS_G_OFF);
  float* biasE        = (float*)(ws + WS_BIAS_OFF);
  uint32_t* mx        = (uint32_t*)(ws + WS_MAX_OFF);

  uint32_t nk[4][2];
#if PART
  for (int i = 0; i < 4; ++i) tf2x32(0u, 42u, 0u, (uint32_t)i, nk[i][0], nk[i][1]);
#else
  {
    uint32_t w0[4], w1[4];
    for (int i = 0; i < 4; ++i) tf2x32(0u, 42u, (uint32_t)i, (uint32_t)(i + 4), w0[i], w1[i]);
    uint32_t out8[8] = {w0[0], w0[1], w0[2], w0[3], w1[0], w1[1], w1[2], w1[3]};
    for (int i = 0; i < 4; ++i) { nk[i][0] = out8[2 * i]; nk[i][1] = out8[2 * i + 1]; }
  }
#endif

  init_max<<<1, 64, 0, stream>>>(mx);
  kmax<<<1024, 256, 0, stream>>>((const float4*)wih, 1048576, mx + 0);
  kmax<<<1024, 256, 0, stream>>>((const float4*)whh, 1048576, mx + 1);
  kmax<<<4, 256, 0, stream>>>((const float4*)bih, 1024, mx + 2);
  kmax<<<4, 256, 0, stream>>>((const float4*)bhh, 1024, mx + 3);

  build_A<<<8192, 256, 0, stream>>>((const float4*)input, (const float4*)hx, A);
  build_B<<<32768, 256, 0, stream>>>(wih, whh, B, mx, nk[0][0], nk[0][1], nk[1][0], nk[1][1]);
  build_bias<<<16, 256, 0, stream>>>(bih, bhh, biasE, mx, nk[2][0], nk[2][1], nk[3][0], nk[3][1]);

  // 128KB dynamic LDS: set attribute every call (idempotent; ignore rc).
  (void)hipFuncSetAttribute((const void*)gemm_gates,
                            hipFuncAttributeMaxDynamicSharedMemorySize, 131072);
  gemm_gates<<<dim3(256), dim3(512), 131072, stream>>>(A, B, biasE, gates);

  float* hy = (float*)d_out;
  float* cyp = hy + (size_t)BATCH * 1024;
  lstm_ew<<<16384, 256, 0, stream>>>(gates, cx, hy, cyp);
}

// Round 3
// 230.629 us; speedup vs baseline: 1.2647x; 1.0127x over previous
//
#include <hip/hip_runtime.h>
#include <hip/hip_bf16.h>
#include <stdint.h>
#include <stddef.h>

// ---------------------------------------------------------------------------
// Quantized LSTM cell (B=4096, I=H=1024) with JAX threefry noise reproduction.
//
// gates = qS8(input) @ (Wih^T + n0) + b_ih + nb0 + qS8(hx) @ (Whh^T + n1) + b_hh + nb1
// ONE bf16 MFMA GEMM, M=N=K=4096:
//   A  [4096][2048] = [qS8(input) | qS8(hx)]          (exact in bf16)
//   B^T[4096][4096] = rows k<2048: bf16_hi(Weff), k>=2048: bf16_lo(Weff)
//   B columns PERMUTED: col' = 4*h + gate  -> LSTM epilogue fused into GEMM
//   (gates buffer never touches HBM).
//
// GEMM: 256x256 tile, BK=32, 8 waves, 4-deep LDS pipeline (128KB dynamic),
// ONE barrier per K-tile, counted vmcnt(4), XOR-swizzled LDS, setprio.
// ---------------------------------------------------------------------------

#define PART 1

typedef __attribute__((ext_vector_type(8))) short bf16x8;
typedef __attribute__((ext_vector_type(4))) float f32x4;

#define BATCH 4096

// ---- workspace layout (bytes) ----
#define WS_A_OFF    ((size_t)0)                 // ushort[4096*2048]   16 MiB
#define WS_B_OFF    ((size_t)16 << 20)          // ushort[4096*4096]   32 MiB
#define WS_BIAS_OFF ((size_t)48 << 20)          // float [4096]
#define WS_MAX_OFF  (WS_BIAS_OFF + 16384)       // uint32[4]

// ---------------- threefry2x32 (exact JAX algorithm) ----------------
__host__ __device__ inline void tf2x32(uint32_t k0, uint32_t k1,
                                       uint32_t x0, uint32_t x1,
                                       uint32_t &o0, uint32_t &o1)
{
  const uint32_t k2 = k0 ^ k1 ^ 0x1BD11BDAu;
#define TFR(r) { x0 += x1; x1 = (x1 << (r)) | (x1 >> (32 - (r))); x1 ^= x0; }
  x0 += k0; x1 += k1;
  TFR(13) TFR(15) TFR(26) TFR(6)
  x0 += k1; x1 += k2 + 1u;
  TFR(17) TFR(29) TFR(16) TFR(24)
  x0 += k2; x1 += k0 + 2u;
  TFR(13) TFR(15) TFR(26) TFR(6)
  x0 += k0; x1 += k1 + 3u;
  TFR(17) TFR(29) TFR(16) TFR(24)
  x0 += k1; x1 += k2 + 4u;
  TFR(13) TFR(15) TFR(26) TFR(6)
  x0 += k2; x1 += k0 + 5u;
#undef TFR
  o0 = x0; o1 = x1;
}

__device__ inline uint32_t jax_bits32(uint32_t k0, uint32_t k1, uint32_t i, uint32_t size)
{
#if PART
  uint32_t a, b;
  tf2x32(k0, k1, 0u, i, a, b);
  return a ^ b;
#else
  uint32_t half = size >> 1, a, b;
  if (i < half) { tf2x32(k0, k1, i, i + half, a, b); return a; }
  tf2x32(k0, k1, i - half, i, a, b); return b;
#endif
}

// uniform(-1+2^-24, 1) -> sqrt(2)*erfinv(u), XLA f32 ErfInv (Giles) polynomial
__device__ inline float bits_to_normal(uint32_t bits)
{
  float f = __uint_as_float((bits >> 9) | 0x3F800000u) - 1.0f;
  const float lo = -0x1.fffffep-1f;
  float u = fmaxf(lo, f * 2.0f + lo);
  float w = -log1pf(-u * u);
  float p;
  if (w < 5.0f) {
    w -= 2.5f;
    p = 2.81022636e-08f;
    p = fmaf(p, w, 3.43273939e-07f);
    p = fmaf(p, w, -3.5233877e-06f);
    p = fmaf(p, w, -4.39150654e-06f);
    p = fmaf(p, w, 0.00021858087f);
    p = fmaf(p, w, -0.00125372503f);
    p = fmaf(p, w, -0.00417768164f);
    p = fmaf(p, w, 0.246640727f);
    p = fmaf(p, w, 1.50140941f);
  } else {
    w = sqrtf(w) - 3.0f;
    p = -0.000200214257f;
    p = fmaf(p, w, 0.000100950558f);
    p = fmaf(p, w, 0.00134934322f);
    p = fmaf(p, w, -0.00367342844f);
    p = fmaf(p, w, 0.00573950773f);
    p = fmaf(p, w, -0.0076224613f);
    p = fmaf(p, w, 0.00943887047f);
    p = fmaf(p, w, 1.00167406f);
    p = fmaf(p, w, 2.83297682f);
  }
  return 0x1.6a09e6p+0f * (p * u);
}

// ---------------- quantization helpers ----------------
__device__ inline float quantS8(float x)
{
  x = fminf(fmaxf(x, -0.9921875f), 0.9921875f);
  return rintf(x * 128.0f) * 0.0078125f;
}
__device__ inline float quantU8(float x)
{
  x = fminf(fmaxf(x, 0.0f), 1.0f);
  return rintf(x * 256.0f) * 0.00390625f;
}
__device__ inline float sigmoid_xla(float x) { return 0.5f + 0.5f * tanhf(0.5f * x); }

__device__ inline unsigned short f2bf(float x)
{
  uint32_t b = __float_as_uint(x);
  return (unsigned short)((b + 0x7FFFu + ((b >> 16) & 1u)) >> 16);
}
__device__ inline float bf2f(unsigned short u) { return __uint_as_float(((uint32_t)u) << 16); }

__device__ inline float dec_max(uint32_t u)
{
  uint32_t bits = (u & 0x80000000u) ? (u ^ 0x80000000u) : ~u;
  return __uint_as_float(bits);
}

// ---------------- small kernels ----------------
__global__ void init_max(uint32_t* mx)
{
  if (threadIdx.x < 4) mx[threadIdx.x] = 0u;
}

__global__ void kmax(const float4* __restrict__ a, int n4, uint32_t* __restrict__ out)
{
  float m = -3.4e38f;
  for (int i = blockIdx.x * blockDim.x + threadIdx.x; i < n4; i += gridDim.x * blockDim.x) {
    float4 v = a[i];
    m = fmaxf(fmaxf(m, fmaxf(v.x, v.y)), fmaxf(v.z, v.w));
  }
  for (int off = 32; off; off >>= 1) m = fmaxf(m, __shfl_down(m, off, 64));
  __shared__ float sm[4];
  if ((threadIdx.x & 63) == 0) sm[threadIdx.x >> 6] = m;
  __syncthreads();
  if (threadIdx.x == 0) {
    float bm = sm[0];
    for (int w = 1; w < (int)(blockDim.x >> 6); ++w) bm = fmaxf(bm, sm[w]);
    uint32_t bits = __float_as_uint(bm);
    uint32_t enc = (bits & 0x80000000u) ? ~bits : (bits | 0x80000000u);
    atomicMax(out, enc);
  }
}

__global__ void build_A(const float4* __restrict__ in, const float4* __restrict__ hx,
                        unsigned short* __restrict__ A)
{
  int t = blockIdx.x * 256 + threadIdx.x;
  int b = t >> 9;
  int kq = t & 511;
  float4 v = (kq < 256) ? in[b * 256 + kq] : hx[b * 256 + (kq - 256)];
  unsigned short o[4];
  o[0] = f2bf(quantS8(v.x)); o[1] = f2bf(quantS8(v.y));
  o[2] = f2bf(quantS8(v.z)); o[3] = f2bf(quantS8(v.w));
  *reinterpret_cast<uint64_t*>(A + (size_t)t * 4) = *reinterpret_cast<uint64_t*>(o);
}

// B^T with PERMUTED columns: original gate-col n (g=n>>10, h=n&1023) is
// stored at row n' = 4h+g.  kc<2048: hi(Weff), kc>=2048: lo residual.
__global__ void build_B(const float* __restrict__ wih, const float* __restrict__ whh,
                        unsigned short* __restrict__ B, const uint32_t* __restrict__ mxenc,
                        uint32_t kih0, uint32_t kih1, uint32_t khh0, uint32_t khh1)
{
  uint32_t t = blockIdx.x * 256u + threadIdx.x;
  uint32_t arr = t >> 22;
  uint32_t r = t & 4194303u;
  uint32_t k = r & 1023u;
  uint32_t n = r >> 10;                       // original gate column
  const float* w = arr ? whh : wih;
  float mx = dec_max(mxenc[arr]);
  uint32_t key0 = arr ? khh0 : kih0, key1 = arr ? khh1 : kih1;
  uint32_t i = k * 4096u + n;                 // noise flat index (orig layout)
  float nrm = bits_to_normal(jax_bits32(key0, key1, i, 4194304u));
  float weff = w[(size_t)n * 1024u + k] + (nrm * mx) * 0.05f;
  unsigned short hi = f2bf(weff);
  unsigned short lob = f2bf(weff - bf2f(hi));
  uint32_t np = (n & 1023u) * 4u + (n >> 10); // permuted column
  size_t base = (size_t)np * 4096u + (arr ? 1024u : 0u) + k;
  B[base] = hi;
  B[base + 2048u] = lob;
}

__global__ void build_bias(const float* __restrict__ bih, const float* __restrict__ bhh,
                           float* __restrict__ biasE, const uint32_t* __restrict__ mxenc,
                           uint32_t kbi0, uint32_t kbi1, uint32_t kbh0, uint32_t kbh1)
{
  uint32_t j = blockIdx.x * 256u + threadIdx.x;
  if (j >= 4096u) return;
  float mi = dec_max(mxenc[2]), mh = dec_max(mxenc[3]);
  float ni = (bits_to_normal(jax_bits32(kbi0, kbi1, j, 4096u)) * mi) * 0.05f;
  float nh = (bits_to_normal(jax_bits32(kbh0, kbh1, j, 4096u)) * mh) * 0.05f;
  biasE[(j & 1023u) * 4u + (j >> 10)] = ((bih[j] + ni) + bhh[j]) + nh;
}

// ---------------- deep-pipelined MFMA GEMM + fused LSTM epilogue ------------
__device__ __forceinline__ void gload_lds16(const void* g, void* l)
{
  __builtin_amdgcn_global_load_lds((__attribute__((address_space(1))) void*)g,
                                   (__attribute__((address_space(3))) void*)l, 16, 0, 0);
}

#define VM4  asm volatile("s_waitcnt vmcnt(4)" ::: "memory")
#define VM0  asm volatile("s_waitcnt vmcnt(0)" ::: "memory")
#define NOVM

// ONE barrier per K-tile.  All 12 frag ds_reads + 4 stage issues up front;
// 32 MFMA gated by compiler-counted lgkmcnt; vmcnt(4) publishes buf t+1.
#define TILE_ONE(t_, DO_STAGE_, VM_ASM_)                                          \
  {                                                                               \
    const int buf_ = (t_) & 3;                                                    \
    const unsigned char* pa_ = lds + buf_ * 32768 + aoff;                         \
    const unsigned char* pb_ = lds + buf_ * 32768 + boff;                         \
    bf16x8 bfr_[4], afL_[4], afH_[4];                                             \
    _Pragma("unroll") for (int n_ = 0; n_ < 4; ++n_)                              \
      bfr_[n_] = *(const bf16x8*)(pb_ + n_ * 1024);                               \
    _Pragma("unroll") for (int m_ = 0; m_ < 4; ++m_)                              \
      afL_[m_] = *(const bf16x8*)(pa_ + m_ * 1024);                               \
    _Pragma("unroll") for (int m_ = 0; m_ < 4; ++m_)                              \
      afH_[m_] = *(const bf16x8*)(pa_ + (4 + m_) * 1024);                         \
    if (DO_STAGE_) {                                                              \
      const int ts_ = (t_) + 2;                                                   \
      unsigned char* la_ = lds + (ts_ & 3) * 32768;                               \
      const int ka_ = (ts_ * 32) & 2047;                                          \
      const size_t kb_ = (size_t)ts_ * 32;                                        \
      gload_lds16(Ar0 + ka_, la_ + tid * 16);                                     \
      gload_lds16(Ar1 + ka_, la_ + 8192 + tid * 16);                              \
      gload_lds16(Br0 + kb_, la_ + 16384 + tid * 16);                             \
      gload_lds16(Br1 + kb_, la_ + 16384 + 8192 + tid * 16);                      \
    }                                                                             \
    __builtin_amdgcn_s_setprio(1);                                                \
    _Pragma("unroll") for (int m_ = 0; m_ < 4; ++m_)                              \
      _Pragma("unroll") for (int n_ = 0; n_ < 4; ++n_)                            \
        acc[m_][n_] = __builtin_amdgcn_mfma_f32_16x16x32_bf16(afL_[m_], bfr_[n_], \
                                                              acc[m_][n_], 0, 0, 0); \
    _Pragma("unroll") for (int m_ = 0; m_ < 4; ++m_)                              \
      _Pragma("unroll") for (int n_ = 0; n_ < 4; ++n_)                            \
        acc[4 + m_][n_] = __builtin_amdgcn_mfma_f32_16x16x32_bf16(afH_[m_], bfr_[n_], \
                                                              acc[4 + m_][n_], 0, 0, 0); \
    __builtin_amdgcn_s_setprio(0);                                                \
    VM_ASM_;                                                                      \
    __builtin_amdgcn_s_barrier();                                                 \
    __builtin_amdgcn_sched_barrier(0);                                            \
  }

__global__ __launch_bounds__(512, 2) void gemm_gates(
    const unsigned short* __restrict__ A,   // [4096][2048] bf16 bits
    const unsigned short* __restrict__ B,   // [4096][4096] bf16 bits, permuted cols
    const float* __restrict__ bias,         // [4096] permuted
    const float* __restrict__ cx,           // [4096][1024]
    float* __restrict__ hy,                 // [4096][1024]
    float* __restrict__ cy)                 // [4096][1024]
{
  extern __shared__ unsigned char lds[];    // 128KB
  const int tid  = threadIdx.x;
  const int lane = tid & 63;
  const int wave = tid >> 6;
  const int wr = wave >> 2;                 // 0..1  (M)
  const int wc = wave & 3;                  // 0..3  (N)

  const int bid = blockIdx.x;
  const int wg  = (bid & 7) * 32 + (bid >> 3);
  const int brow = (wg & 15) * 256;
  const int bcol = (wg >> 4) * 256;

  // staging source (inverse-swizzled): chunk c -> p=c>>3, lc=(c&7)^(p&7)
  int sr0, sk0, sr1, sk1;
  {
    int c = tid, p = c >> 3, lc = (c & 7) ^ (p & 7);
    sr0 = p * 2 + (lc >> 2); sk0 = (lc & 3) * 8;
    c = tid + 512; p = c >> 3; lc = (c & 7) ^ (p & 7);
    sr1 = p * 2 + (lc >> 2); sk1 = (lc & 3) * 8;
  }
  const unsigned short* Ar0 = A + (size_t)(brow + sr0) * 2048 + sk0;
  const unsigned short* Ar1 = A + (size_t)(brow + sr1) * 2048 + sk1;
  const unsigned short* Br0 = B + (size_t)(bcol + sr0) * 4096 + sk0;
  const unsigned short* Br1 = B + (size_t)(bcol + sr1) * 4096 + sk1;

  const int lrh = (lane & 15) >> 1;
  const int chk = ((((lane & 1) << 2) | (lane >> 4)) ^ lrh);
  const int aoff = wr * 8192 + lrh * 128 + chk * 16;
  const int boff = 16384 + wc * 4096 + lrh * 128 + chk * 16;

  f32x4 acc[8][4] = {};

  // prologue: stage tiles 0,1
#pragma unroll
  for (int tt = 0; tt < 2; ++tt) {
    unsigned char* la = lds + tt * 32768;
    const int ka = tt * 32;
    gload_lds16(Ar0 + ka, la + tid * 16);
    gload_lds16(Ar1 + ka, la + 8192 + tid * 16);
    gload_lds16(Br0 + (size_t)(tt * 32), la + 16384 + tid * 16);
    gload_lds16(Br1 + (size_t)(tt * 32), la + 16384 + 8192 + tid * 16);
  }
  VM4;
  __builtin_amdgcn_s_barrier();
  __builtin_amdgcn_sched_barrier(0);

#pragma unroll 1
  for (int t = 0; t < 126; ++t) {
    TILE_ONE(t, 1, VM4);
  }
  TILE_ONE(126, 0, VM0);
  TILE_ONE(127, 0, NOVM);

  // ---- fused LSTM epilogue ----
  // acc[am][n] row = brow + wr*128 + am*16 + (lane>>4)*4 + r
  //            col = bcol + wc*64 + n*16 + (lane&15)   (permuted: col = 4h+g)
  // Two halves (am 0..3, 4..7), each staged to LDS as [128 local rows][256 cols] f32.
  float* LT = (float*)lds;
  const int col_local0 = wc * 64 + (lane & 15);
  const int lrow = (lane >> 4) << 2;
  const int h = tid & 63;
  const int hg = (bcol >> 2) + h;

#pragma unroll
  for (int hh = 0; hh < 2; ++hh) {
    __syncthreads();                       // previous half's reads done
#pragma unroll
    for (int m = 0; m < 4; ++m) {
#pragma unroll
      for (int n = 0; n < 4; ++n) {
        const int cl = col_local0 + n * 16;
        const float bv = bias[bcol + cl];
        const int lr0 = wr * 64 + m * 16 + lrow;
#pragma unroll
        for (int r = 0; r < 4; ++r)
          LT[(lr0 + r) * 256 + cl] = acc[hh * 4 + m][n][r] + bv;
      }
    }
    __syncthreads();
#pragma unroll
    for (int i = 0; i < 16; ++i) {
      const int lr = (tid >> 6) * 16 + i;                       // 0..127
      const int grow = brow + ((lr >> 6) << 7) + hh * 64 + (lr & 63);
      const float4 q = *(const float4*)(LT + lr * 256 + 4 * h); // (in,fg,cell,out)
      const size_t oidx = (size_t)grow * 1024 + hg;
      float ing = quantU8(sigmoid_xla(q.x));
      float fg  = quantU8(sigmoid_xla(q.y));
      float cg  = quantS8(tanhf(q.z));
      float og  = quantU8(sigmoid_xla(q.w));
      float c0  = cx[oidx];
      float cyv = quantS8((quantS8(fg * c0) + quantS8(ing * cg)) * 0.5f);
      float hyv = quantS8(og * quantS8(tanhf(cyv * 2.0f)));
      hy[oidx] = hyv;
      cy[oidx] = cyv;
    }
  }
}

// ---------------- host ----------------
extern "C" void kernel_launch(void* const* d_in, const int* in_sizes, int n_in,
                              void* d_out, int out_size, void* d_ws, size_t ws_size,
                              hipStream_t stream)
{
  const float* input = (const float*)d_in[0];
  const float* hx    = (const float*)d_in[1];
  const float* cx    = (const float*)d_in[2];
  const float* wih   = (const float*)d_in[3];
  const float* whh   = (const float*)d_in[4];
  const float* bih   = (const float*)d_in[5];
  const float* bhh   = (const float*)d_in[6];
  (void)in_sizes; (void)n_in; (void)ws_size;

  uint8_t* ws = (uint8_t*)d_ws;
  unsigned short* A   = (unsigned short*)(ws + WS_A_OFF);
  unsigned short* B   = (unsigned short*)(ws + WS_B_OFF);
  float* biasE        = (float*)(ws + WS_BIAS_OFF);
  uint32_t* mx        = (uint32_t*)(ws + WS_MAX_OFF);

  uint32_t nk[4][2];
#if PART
  for (int i = 0; i < 4; ++i) tf2x32(0u, 42u, 0u, (uint32_t)i, nk[i][0], nk[i][1]);
#else
  {
    uint32_t w0[4], w1[4];
    for (int i = 0; i < 4; ++i) tf2x32(0u, 42u, (uint32_t)i, (uint32_t)(i + 4), w0[i], w1[i]);
    uint32_t out8[8] = {w0[0], w0[1], w0[2], w0[3], w1[0], w1[1], w1[2], w1[3]};
    for (int i = 0; i < 4; ++i) { nk[i][0] = out8[2 * i]; nk[i][1] = out8[2 * i + 1]; }
  }
#endif

  init_max<<<1, 64, 0, stream>>>(mx);
  kmax<<<1024, 256, 0, stream>>>((const float4*)wih, 1048576, mx + 0);
  kmax<<<1024, 256, 0, stream>>>((const float4*)whh, 1048576, mx + 1);
  kmax<<<4, 256, 0, stream>>>((const float4*)bih, 1024, mx + 2);
  kmax<<<4, 256, 0, stream>>>((const float4*)bhh, 1024, mx + 3);

  build_A<<<8192, 256, 0, stream>>>((const float4*)input, (const float4*)hx, A);
  build_B<<<32768, 256, 0, stream>>>(wih, whh, B, mx, nk[0][0], nk[0][1], nk[1][0], nk[1][1]);
  build_bias<<<16, 256, 0, stream>>>(bih, bhh, biasE, mx, nk[2][0], nk[2][1], nk[3][0], nk[3][1]);

  float* hy = (float*)d_out;
  float* cyp = hy + (size_t)BATCH * 1024;

  (void)hipFuncSetAttribute((const void*)gemm_gates,
                            hipFuncAttributeMaxDynamicSharedMemorySize, 131072);
  gemm_gates<<<dim3(256), dim3(512), 131072, stream>>>(A, B, biasE, cx, hy, cyp);
}